// Round 14
// baseline (355.168 us; speedup 1.0000x reference)
//
#include <hip/hip_runtime.h>

#define B_SZ 2048
#define D_IN 256
#define L_N 48
#define H_N 256
#define O_N 10
#define WROW 303      // D + L - 1
#define LEAF_N 12336  // L*(D+1)
#define KTRI 1176     // 48*49/2 packed lower-tri cols
#define KH2 1224      // KTRI + 48 offs cols
#define KPAD2 1280    // padded K (20 x 64)

using short8 = __attribute__((ext_vector_type(8))) short;
using f32x4  = __attribute__((ext_vector_type(4))) float;

__device__ inline void bf16_split(float v, unsigned short& h, unsigned short& l) {
  unsigned bits = __float_as_uint(v);
  h = (unsigned short)(bits >> 16);
  float hf = __uint_as_float(bits & 0xFFFF0000u);
  float r = v - hf;
  l = (unsigned short)(__float_as_uint(r) >> 16);
}
__device__ inline unsigned short bf16_hi(float v) {
  return (unsigned short)(__float_as_uint(v) >> 16);
}

// ---------------------------------------------------------------------------
// Kernel 1a: ghat -- 96 blocks x 512 thr; 2 layers (i0,i1) per block;
// waves 0-3 compute i0, waves 4-7 compute i1 (shared Bt). Tri-skip per wave.
// ---------------------------------------------------------------------------
__global__ __launch_bounds__(512) void k_ghat(const float* __restrict__ W,
                                              const float* __restrict__ Wb0,
                                              unsigned short* __restrict__ Gh) {
  __shared__ float smem[13056];
  float (*At0)[68] = (float(*)[68])smem;
  float (*At1)[68] = (float(*)[68])(smem + 4352);
  float (*Bt)[68]  = (float(*)[68])(smem + 8704);
  const int bid = blockIdx.x;
  const int t = threadIdx.x;
  const int i0 = (bid % 24) * 2, i1 = i0 + 1;
  const int h0 = (bid / 24) * 64;
  const int w = t >> 6;
  const int wl = w & 3;
  const int ih = w >> 2;
  const int i = ih ? i1 : i0;
  const int lane = t & 63;
  const int hq = lane & 15, kq = lane >> 4;
  const int sr = t & 3, scc = t >> 2;
  const int sc = scc & 63;
  const bool wactive = (16 * wl) <= i;
  float acc[4][4] = {};
  for (int dc = 0; dc < 256; dc += 64) {
    __syncthreads();
#pragma unroll
    for (int j = 0; j < 16; ++j) {
      int r = sr + j * 4;
      if (scc < 64) {
        At0[sc][r] = Wb0[(size_t)(h0 + r) * LEAF_N + i0 * 257 + dc + sc];
        Bt[sc][r] = (r < 48) ? W[r * WROW + dc + sc] : 0.f;
      } else {
        At1[sc][r] = Wb0[(size_t)(h0 + r) * LEAF_N + i1 * 257 + dc + sc];
      }
    }
    __syncthreads();
    if (wactive) {
      float (*At)[68] = ih ? At1 : At0;
#pragma unroll 8
      for (int d = 0; d < 64; ++d) {
        float4 av = *(const float4*)&At[d][hq * 4];
        float4 bv = *(const float4*)&Bt[d][wl * 16 + kq * 4];
        float aa[4] = {av.x, av.y, av.z, av.w};
        float bb[4] = {bv.x, bv.y, bv.z, bv.w};
#pragma unroll
        for (int ii = 0; ii < 4; ++ii)
#pragma unroll
          for (int jj = 0; jj < 4; ++jj) acc[ii][jj] += aa[ii] * bb[jj];
      }
    }
  }
  if (wactive) {
    int tb = i * (i + 1) / 2;
#pragma unroll
    for (int ii = 0; ii < 4; ++ii) {
      size_t hrow = (size_t)(h0 + hq * 4 + ii) * KPAD2;
#pragma unroll
      for (int jj = 0; jj < 4; ++jj) {
        int k = wl * 16 + kq * 4 + jj;
        if (k <= i) Gh[hrow + tb + k] = bf16_hi(acc[ii][jj]);
      }
    }
  }
  if (t < 64)
    Gh[(size_t)(h0 + t) * KPAD2 + KTRI + i0] =
        bf16_hi(Wb0[(size_t)(h0 + t) * LEAF_N + i0 * 257 + 256]);
  else if (t < 128)
    Gh[(size_t)(h0 + t - 64) * KPAD2 + KTRI + i1] =
        bf16_hi(Wb0[(size_t)(h0 + t - 64) * LEAF_N + i1 * 257 + 256]);
  if (i0 == 0) {
    for (int e = t; e < 64 * (KPAD2 - KH2); e += 512) {
      int r = e / (KPAD2 - KH2), c = e - r * (KPAD2 - KH2);
      Gh[(size_t)(h0 + r) * KPAD2 + KH2 + c] = 0;
    }
  }
}

// ---------------------------------------------------------------------------
// Kernel 1b: seq -- 256 blocks x 512 thr (8 waves, one batch row each).
// W staged in LDS once per block. Solve is BRANCHLESS straight-line code
// (compute every row, scale by fm_i in {0,1}) with wrow read from LDS --
// no global s_loads, no data-dependent branches (I-stream friendly).
// ---------------------------------------------------------------------------
__global__ __launch_bounds__(512) void k_seq(const float* __restrict__ W,
                                             const float* __restrict__ x,
                                             const float* __restrict__ bvec,
                                             unsigned short* __restrict__ Ch,
                                             unsigned short* __restrict__ Cl,
                                             float* __restrict__ mask_out) {
  __shared__ float WL[48 * WROW];  // 58,176 B
  const int t = threadIdx.x;
  for (int e = t; e < 48 * WROW; e += 512) WL[e] = W[e];
  __syncthreads();
  const int w_u = __builtin_amdgcn_readfirstlane(t >> 6);
  const int b = blockIdx.x * 8 + w_u;
  const int lane = t & 63;
  const int lrow = (lane < 48) ? lane : 0;  // clamp to stay in WL

  // P: lane i dots x[b,:] (scalar loads, xr uniform) with WL row i
  const float* xr = x + (size_t)b * D_IN;
  const float* wr = WL + lrow * WROW;
  float a0 = 0.f, a1 = 0.f, a2 = 0.f, a3 = 0.f;
#pragma unroll 8
  for (int d = 0; d < 256; d += 4) {
    a0 = fmaf(xr[d + 0], wr[d + 0], a0);
    a1 = fmaf(xr[d + 1], wr[d + 1], a1);
    a2 = fmaf(xr[d + 2], wr[d + 2], a2);
    a3 = fmaf(xr[d + 3], wr[d + 3], a3);
  }
  float Preg = (lane < 48) ? (a0 + a1) + (a2 + a3) : 0.f;
  float Pb = Preg + ((lane < 48) ? bvec[lane] : 0.f);

  // z/u recurrences (unrolled: serial readlane chain, latency-critical)
  const float* mywh = wr + 256;
  float accA = 0.f, accB = 0.f, offs_lane = 0.f;
  int d_lane = 0;
#pragma unroll
  for (int i = 0; i < 48; ++i) {
    float z = Pb + accA;
    float u = Preg + accB;
    float a_i = fmaxf(z, 0.f);
    bool dpos = z > 0.f;
    float o_i = dpos ? u : 0.f;
    if (lane == i) {
      d_lane = dpos ? 1 : 0;
      offs_lane = a_i - o_i;
    }
    float ab = __shfl(a_i, i);
    float ob = __shfl(o_i, i);
    if (i < 47) {
      float whk = (lane < 48) ? mywh[i] : 0.f;
      accA += whk * ab;
      accB += whk * ob;
    }
  }
  unsigned long long dmask = __ballot(d_lane);

  // branchless solve: s[i] = fm_i * (sum_{k<i} wh_i[k] s[k] + (lane==i))
  float s[48];
  s[0] = ((dmask & 1ULL) && lane == 0) ? 1.f : 0.f;
#pragma unroll
  for (int i = 1; i < 48; ++i) {
    const float* wrow = WL + i * WROW + 256;  // uniform LDS base -> broadcast
    float t0 = (lane == i) ? 1.f : 0.f;
    float t1 = 0.f, t2 = 0.f, t3 = 0.f;
    int k = 0;
#pragma unroll
    for (; k + 3 < i; k += 4) {
      t0 = fmaf(wrow[k + 0], s[k + 0], t0);
      t1 = fmaf(wrow[k + 1], s[k + 1], t1);
      t2 = fmaf(wrow[k + 2], s[k + 2], t2);
      t3 = fmaf(wrow[k + 3], s[k + 3], t3);
    }
#pragma unroll
    for (; k < i; ++k) t0 = fmaf(wrow[k], s[k], t0);
    float fm = ((dmask >> i) & 1ULL) ? 1.f : 0.f;
    s[i] = fm * ((t0 + t1) + (t2 + t3));
  }

  // packed-tri stores: j = i(i+1)/2 + lane (lane<=i), bf16 hi/lo
  size_t base = (size_t)b * KPAD2;
  if (lane < 48) {
#pragma unroll
    for (int i = 0; i < 48; ++i) {
      if (lane <= i) {
        unsigned short h, l;
        bf16_split(s[i], h, l);
        Ch[base + i * (i + 1) / 2 + lane] = h;
        Cl[base + i * (i + 1) / 2 + lane] = l;
      }
    }
    unsigned short h, l;
    bf16_split(offs_lane, h, l);
    Ch[base + KTRI + lane] = h;
    Cl[base + KTRI + lane] = l;
    mask_out[b * 48 + lane] = d_lane ? 1.f : 0.f;
  }
  for (int e = KH2 + lane; e < KPAD2; e += 64) {
    Ch[base + e] = 0;
    Cl[base + e] = 0;
  }
}

// ---------------------------------------------------------------------------
// Kernel 2: big GEMM, 2-term bf16 MFMA: acc = Ah*Bh + Al*Bh.
// 4 waves, LDS-staged, LDSP=88. K=1280 split 4x320. XCD-chunk-swizzled.
// ---------------------------------------------------------------------------
#define LDSP 88
__global__ __launch_bounds__(256) void k_gemm_bf16(
    const unsigned short* __restrict__ Ah, const unsigned short* __restrict__ Al,
    const unsigned short* __restrict__ Bh,
    float* __restrict__ part) {
  int flat = blockIdx.x + 32 * blockIdx.y + 128 * blockIdx.z;  // 0..511
  int id = (flat & 7) * 64 + (flat >> 3);                      // XCD chunks
  const int bz = id & 3, by = (id >> 2) & 3, bx = id >> 4;
  const int m0 = bx * 64;
  const int n0 = by * 64;
  const int k0 = bz * 320;
  float* dst = part + (size_t)bz * ((size_t)B_SZ * H_N);
  __shared__ unsigned short AhL[64 * LDSP], AlL[64 * LDSP];
  __shared__ unsigned short BhL[64 * LDSP];
  const int t = threadIdx.x;
  const int lane = t & 63;
  const int w = t >> 6;
  const int fr = lane & 15;
  const int fq = lane >> 4;
  f32x4 acc[4] = {};
  for (int it = 0; it < 5; ++it) {
    int kb = k0 + it * 64;
#pragma unroll
    for (int j = 0; j < 2; ++j) {
      int c = t + j * 256;
      int row = c >> 3, ko = (c & 7) * 8;
      size_t ga = (size_t)(m0 + row) * KPAD2 + kb + ko;
      size_t gb = (size_t)(n0 + row) * KPAD2 + kb + ko;
      *(short8*)&AhL[row * LDSP + ko] = *(const short8*)&Ah[ga];
      *(short8*)&AlL[row * LDSP + ko] = *(const short8*)&Al[ga];
      *(short8*)&BhL[row * LDSP + ko] = *(const short8*)&Bh[gb];
    }
    __syncthreads();
#pragma unroll
    for (int ks = 0; ks < 2; ++ks) {
      int aoff = (w * 16 + fr) * LDSP + fq * 8 + ks * 32;
      short8 ah = *(const short8*)&AhL[aoff];
      short8 al = *(const short8*)&AlL[aoff];
#pragma unroll
      for (int nt = 0; nt < 4; ++nt) {
        int boff = (nt * 16 + fr) * LDSP + fq * 8 + ks * 32;
        short8 bh = *(const short8*)&BhL[boff];
        acc[nt] = __builtin_amdgcn_mfma_f32_16x16x32_bf16(ah, bh, acc[nt], 0, 0, 0);
        acc[nt] = __builtin_amdgcn_mfma_f32_16x16x32_bf16(al, bh, acc[nt], 0, 0, 0);
      }
    }
    __syncthreads();
  }
  // C layout: col = lane&15, row = (lane>>4)*4 + reg  [m89-verified]
  int mrow = m0 + w * 16 + fq * 4;
#pragma unroll
  for (int nt = 0; nt < 4; ++nt) {
    int ncol = n0 + nt * 16 + fr;
#pragma unroll
    for (int r = 0; r < 4; ++r)
      dst[(size_t)(mrow + r) * H_N + ncol] = acc[nt][r];
  }
}

// ---------------------------------------------------------------------------
// Kernel 3: h1 = relu( relu(sum_z part_z + bb0) @ Wb1^T + bb1 ) via bf16
// MFMA; fused reduce+bias+relu+bf16 in A-staging. BM=64 BN=32, 4 waves.
// ---------------------------------------------------------------------------
#define LDSP2 72
__global__ __launch_bounds__(256) void k_gemm2b(const float* __restrict__ part,
                                                const float* __restrict__ bb0,
                                                const float* __restrict__ Bm,
                                                const float* __restrict__ bias,
                                                float* __restrict__ h1) {
  int flat = blockIdx.x + 32 * blockIdx.y;      // 0..255
  int id = (flat & 7) * 32 + (flat >> 3);       // XCD chunks, x slowest
  const int m0 = (id >> 3) * 64;
  const int n0 = (id & 7) * 32;
  const size_t BH = (size_t)B_SZ * H_N;
  __shared__ unsigned short AtL[64 * LDSP2];
  __shared__ unsigned short BtL[32 * LDSP2];
  const int t = threadIdx.x;
  const int lane = t & 63;
  const int w = t >> 6;
  const int fr = lane & 15;
  const int fq = lane >> 4;
  f32x4 acc[2] = {};
  for (int it = 0; it < 4; ++it) {
    int kb = it * 64;
#pragma unroll
    for (int j = 0; j < 4; ++j) {
      int g = t + j * 256;
      int row = g >> 4, c4 = g & 15;
      size_t base = (size_t)(m0 + row) * H_N + kb + c4 * 4;
      float4 v0 = *(const float4*)&part[base];
      float4 v1 = *(const float4*)&part[base + BH];
      float4 v2 = *(const float4*)&part[base + 2 * BH];
      float4 v3 = *(const float4*)&part[base + 3 * BH];
      float4 bi = *(const float4*)&bb0[kb + c4 * 4];
      ushort4 o;
      o.x = bf16_hi(fmaxf(v0.x + v1.x + v2.x + v3.x + bi.x, 0.f));
      o.y = bf16_hi(fmaxf(v0.y + v1.y + v2.y + v3.y + bi.y, 0.f));
      o.z = bf16_hi(fmaxf(v0.z + v1.z + v2.z + v3.z + bi.z, 0.f));
      o.w = bf16_hi(fmaxf(v0.w + v1.w + v2.w + v3.w + bi.w, 0.f));
      *(ushort4*)&AtL[row * LDSP2 + c4 * 4] = o;
    }
#pragma unroll
    for (int j = 0; j < 2; ++j) {
      int g = t + j * 256;
      int row = g >> 4, c4 = g & 15;
      float4 v = *(const float4*)&Bm[(size_t)(n0 + row) * H_N + kb + c4 * 4];
      ushort4 o;
      o.x = bf16_hi(v.x); o.y = bf16_hi(v.y);
      o.z = bf16_hi(v.z); o.w = bf16_hi(v.w);
      *(ushort4*)&BtL[row * LDSP2 + c4 * 4] = o;
    }
    __syncthreads();
#pragma unroll
    for (int ks = 0; ks < 2; ++ks) {
      short8 a8 = *(const short8*)&AtL[(w * 16 + fr) * LDSP2 + fq * 8 + ks * 32];
#pragma unroll
      for (int nt = 0; nt < 2; ++nt) {
        short8 b8 =
            *(const short8*)&BtL[(nt * 16 + fr) * LDSP2 + fq * 8 + ks * 32];
        acc[nt] = __builtin_amdgcn_mfma_f32_16x16x32_bf16(a8, b8, acc[nt], 0, 0, 0);
      }
    }
    __syncthreads();
  }
  int mrow = m0 + w * 16 + fq * 4;
#pragma unroll
  for (int nt = 0; nt < 2; ++nt) {
    int ncol = n0 + nt * 16 + fr;
    float bs = bias[ncol];
#pragma unroll
    for (int r = 0; r < 4; ++r)
      h1[(size_t)(mrow + r) * H_N + ncol] = fmaxf(acc[nt][r] + bs, 0.f);
  }
}

// ---------------------------------------------------------------------------
// Kernel 4: out[b,:] = h1[b,:] @ Wout^T + bout. One wave per batch row.
// ---------------------------------------------------------------------------
__global__ __launch_bounds__(256) void k_out(const float* __restrict__ h1,
                                             const float* __restrict__ Wout,
                                             const float* __restrict__ bout,
                                             float* __restrict__ out) {
  int w = threadIdx.x >> 6, lane = threadIdx.x & 63;
  int b = blockIdx.x * 4 + w;
  const float* hr = h1 + (size_t)b * H_N;
  float h[4];
#pragma unroll
  for (int j = 0; j < 4; ++j) h[j] = hr[lane + 64 * j];
  float acc[10];
#pragma unroll
  for (int o = 0; o < 10; ++o) {
    float s = 0.f;
#pragma unroll
    for (int j = 0; j < 4; ++j) s += h[j] * Wout[o * H_N + lane + 64 * j];
#pragma unroll
    for (int m = 32; m >= 1; m >>= 1) s += __shfl_xor(s, m);
    acc[o] = s;
  }
  if (lane == 0) {
#pragma unroll
    for (int o = 0; o < 10; ++o) out[(size_t)b * O_N + o] = acc[o] + bout[o];
  }
}

// ---------------------------------------------------------------------------
extern "C" void kernel_launch(void* const* d_in, const int* in_sizes, int n_in,
                              void* d_out, int out_size, void* d_ws,
                              size_t ws_size, hipStream_t stream) {
  (void)in_sizes; (void)n_in; (void)out_size; (void)ws_size;
  const float* x    = (const float*)d_in[0];
  const float* W    = (const float*)d_in[1];
  const float* bvec = (const float*)d_in[2];
  const float* Wb0  = (const float*)d_in[3];
  const float* bb0  = (const float*)d_in[4];
  const float* Wb1  = (const float*)d_in[5];
  const float* bb1  = (const float*)d_in[6];
  const float* Wout = (const float*)d_in[7];
  const float* bout = (const float*)d_in[8];

  float* out   = (float*)d_out;     // B*10
  float* masks = out + B_SZ * O_N;  // B*48

  char* wsb = (char*)d_ws;
  unsigned short* Ch = (unsigned short*)wsb;                // B*KPAD2 us
  unsigned short* Cl = Ch + (size_t)B_SZ * KPAD2;
  unsigned short* Gh = Cl + (size_t)B_SZ * KPAD2;           // H*KPAD2 us
  float* part = (float*)(Gh + (size_t)H_N * KPAD2);         // 4*B*H f32
  float* h1 = part + 4 * (size_t)B_SZ * H_N;                // B*H f32
  // total ~22 MB

  k_ghat<<<dim3(96), 512, 0, stream>>>(W, Wb0, Gh);
  k_seq<<<dim3(256), 512, 0, stream>>>(W, x, bvec, Ch, Cl, masks);
  k_gemm_bf16<<<dim3(32, 4, 4), 256, 0, stream>>>(Ch, Cl, Gh, part);
  k_gemm2b<<<dim3(32, 8), 256, 0, stream>>>(part, bb0, Wb1, bb1, h1);
  k_out<<<dim3(512), 256, 0, stream>>>(h1, Wout, bout, out);
}

// Round 17
// 73.362 us; speedup vs baseline: 4.8413x; 4.8413x over previous
//
#include <hip/hip_runtime.h>

#define B_SZ 2048
#define D_IN 256
#define L_N 48
#define H_N 256
#define O_N 10
#define WROW 303      // D + L - 1
#define LEAF_N 12336  // L*(D+1)
#define KTRI 1176     // 48*49/2 packed lower-tri cols
#define KH2 1224      // KTRI + 48 offs cols
#define KPAD2 1280    // padded K (20 x 64)

using short8 = __attribute__((ext_vector_type(8))) short;
using f32x4  = __attribute__((ext_vector_type(4))) float;

__device__ inline void bf16_split(float v, unsigned short& h, unsigned short& l) {
  unsigned bits = __float_as_uint(v);
  h = (unsigned short)(bits >> 16);
  float hf = __uint_as_float(bits & 0xFFFF0000u);
  float r = v - hf;
  l = (unsigned short)(__float_as_uint(r) >> 16);
}
__device__ inline unsigned short bf16_hi(float v) {
  return (unsigned short)(__float_as_uint(v) >> 16);
}

// ---------------------------------------------------------------------------
// Kernel 1a: ghat (R12-proven form) -- 192 blocks x 256 thr; per (i, h-tile)
// full-K=256 GEMM in 4 staged rounds; wave w owns k-cols [16w,16w+16),
// skipped when 16w > i (lower-tri). + offs col + pad (i==0 blocks).
// ---------------------------------------------------------------------------
__global__ __launch_bounds__(256) void k_ghat(const float* __restrict__ W,
                                              const float* __restrict__ Wb0,
                                              unsigned short* __restrict__ Gh) {
  __shared__ float At[64][68];  // [d][h]
  __shared__ float Bt[64][68];  // [d][k] (k>=48 zero)
  const int bid = blockIdx.x;
  const int t = threadIdx.x;
  const int i  = bid % 48;
  const int h0 = (bid / 48) * 64;
  const int w = t >> 6;        // wave -> k-group [16w, 16w+16)
  const int lane = t & 63;
  const int hq = lane & 15;
  const int kq = lane >> 4;
  const int sr = t & 3, sc = t >> 2;
  const bool wactive = (16 * w) <= i;
  float acc[4][4] = {};
  for (int dc = 0; dc < 256; dc += 64) {
    __syncthreads();
#pragma unroll
    for (int j = 0; j < 16; ++j) {
      int r = sr + j * 4;
      At[sc][r] = Wb0[(size_t)(h0 + r) * LEAF_N + i * 257 + dc + sc];
      Bt[sc][r] = (r < 48) ? W[r * WROW + dc + sc] : 0.f;
    }
    __syncthreads();
    if (wactive) {
#pragma unroll 8
      for (int d = 0; d < 64; ++d) {
        float4 av = *(const float4*)&At[d][hq * 4];
        float4 bv = *(const float4*)&Bt[d][w * 16 + kq * 4];
        float aa[4] = {av.x, av.y, av.z, av.w};
        float bb[4] = {bv.x, bv.y, bv.z, bv.w};
#pragma unroll
        for (int ii = 0; ii < 4; ++ii)
#pragma unroll
          for (int jj = 0; jj < 4; ++jj) acc[ii][jj] += aa[ii] * bb[jj];
      }
    }
  }
  if (wactive) {
    int tb = i * (i + 1) / 2;
#pragma unroll
    for (int ii = 0; ii < 4; ++ii) {
      size_t hrow = (size_t)(h0 + hq * 4 + ii) * KPAD2;
#pragma unroll
      for (int jj = 0; jj < 4; ++jj) {
        int k = w * 16 + kq * 4 + jj;
        if (k <= i) Gh[hrow + tb + k] = bf16_hi(acc[ii][jj]);
      }
    }
  }
  if (t < 64)  // offs column for this i
    Gh[(size_t)(h0 + t) * KPAD2 + KTRI + i] =
        bf16_hi(Wb0[(size_t)(h0 + t) * LEAF_N + i * 257 + 256]);
  if (i == 0) {  // pad [KH2, KPAD2)
    for (int e = t; e < 64 * (KPAD2 - KH2); e += 256) {
      int r = e / (KPAD2 - KH2), c = e - r * (KPAD2 - KH2);
      Gh[(size_t)(h0 + r) * KPAD2 + KH2 + c] = 0;
    }
  }
}

// ---------------------------------------------------------------------------
// Kernel 1b: seq (R12-proven form) -- 512 blocks x 256 thr, 4 waves, one
// batch row per wave. In-wave P (global W reads); solve with wave-uniform
// GLOBAL s_loads (values live in SGPRs -- no VGPR pressure/spill).
// ---------------------------------------------------------------------------
__global__ __launch_bounds__(256) void k_seq(const float* __restrict__ W,
                                             const float* __restrict__ x,
                                             const float* __restrict__ bvec,
                                             unsigned short* __restrict__ Ch,
                                             unsigned short* __restrict__ Cl,
                                             float* __restrict__ mask_out) {
  const int t = threadIdx.x;
  const int b = blockIdx.x * 4 + (t >> 6);
  const int lane = t & 63;

  // in-wave P: lane i = dot(x[b,:], W[i,0:256]); x loads wave-uniform
  float Preg = 0.f;
  if (lane < 48) {
    const float* xr = x + (size_t)b * D_IN;
    const float* wr = W + lane * WROW;
    float a0 = 0.f, a1 = 0.f, a2 = 0.f, a3 = 0.f;
#pragma unroll 4
    for (int d = 0; d < 256; d += 4) {
      a0 = fmaf(xr[d + 0], wr[d + 0], a0);
      a1 = fmaf(xr[d + 1], wr[d + 1], a1);
      a2 = fmaf(xr[d + 2], wr[d + 2], a2);
      a3 = fmaf(xr[d + 3], wr[d + 3], a3);
    }
    Preg = (a0 + a1) + (a2 + a3);
  }

  float whr[47];
#pragma unroll
  for (int k = 0; k < 47; ++k)
    whr[k] = (lane < 48) ? W[lane * WROW + 256 + k] : 0.f;

  float Pb = Preg + ((lane < 48) ? bvec[lane] : 0.f);

  float accA = 0.f, accB = 0.f;
  float offs_lane = 0.f;
  int d_lane = 0;
#pragma unroll
  for (int i = 0; i < 48; ++i) {
    float z = Pb + accA;
    float u = Preg + accB;
    float a_i = fmaxf(z, 0.f);
    bool dpos = z > 0.f;
    float o_i = dpos ? u : 0.f;
    if (lane == i) {
      d_lane = dpos ? 1 : 0;
      offs_lane = a_i - o_i;
    }
    float ab = __shfl(a_i, i);
    float ob = __shfl(o_i, i);
    if (i < 47) {
      accA += whr[i] * ab;
      accB += whr[i] * ob;
    }
  }
  unsigned long long dmask = __ballot(d_lane);

  // solve: s[i] = d_i * (sum_{k<i} wh_i[k] s[k] + (i==lane)); wrow via
  // wave-uniform GLOBAL loads -> s_load -> SGPR (critical: no VGPR spill)
  float s[48];
  s[0] = ((dmask & 1ULL) && lane == 0) ? 1.f : 0.f;
#pragma unroll
  for (int i = 1; i < 48; ++i) {
    if ((dmask >> i) & 1ULL) {
      const float* wrow = W + i * WROW + 256;
      float t0 = (lane == i) ? 1.f : 0.f;
      float t1 = 0.f, t2 = 0.f, t3 = 0.f;
      int k = 0;
#pragma unroll
      for (; k + 3 < i; k += 4) {
        t0 += wrow[k + 0] * s[k + 0];
        t1 += wrow[k + 1] * s[k + 1];
        t2 += wrow[k + 2] * s[k + 2];
        t3 += wrow[k + 3] * s[k + 3];
      }
#pragma unroll
      for (; k < i; ++k) t0 += wrow[k] * s[k];
      s[i] = (t0 + t1) + (t2 + t3);
    } else {
      s[i] = 0.f;
    }
  }

  // packed-tri stores: j = i(i+1)/2 + lane (lane<=i), bf16 hi/lo
  size_t base = (size_t)b * KPAD2;
  if (lane < 48) {
#pragma unroll
    for (int i = 0; i < 48; ++i) {
      if (lane <= i) {
        unsigned short h, l;
        bf16_split(s[i], h, l);
        Ch[base + i * (i + 1) / 2 + lane] = h;
        Cl[base + i * (i + 1) / 2 + lane] = l;
      }
    }
    unsigned short h, l;
    bf16_split(offs_lane, h, l);
    Ch[base + KTRI + lane] = h;
    Cl[base + KTRI + lane] = l;
    mask_out[b * 48 + lane] = d_lane ? 1.f : 0.f;
  }
  for (int e = KH2 + lane; e < KPAD2; e += 64) {
    Ch[base + e] = 0;
    Cl[base + e] = 0;
  }
}

// ---------------------------------------------------------------------------
// Kernel 2: big GEMM, 2-term bf16 MFMA: acc = Ah*Bh + Al*Bh.
// 4 waves, LDS-staged, LDSP=88. K=1280 split 4x320. XCD-chunk-swizzled.
// ---------------------------------------------------------------------------
#define LDSP 88
__global__ __launch_bounds__(256) void k_gemm_bf16(
    const unsigned short* __restrict__ Ah, const unsigned short* __restrict__ Al,
    const unsigned short* __restrict__ Bh,
    float* __restrict__ part) {
  int flat = blockIdx.x + 32 * blockIdx.y + 128 * blockIdx.z;  // 0..511
  int id = (flat & 7) * 64 + (flat >> 3);                      // XCD chunks
  const int bz = id & 3, by = (id >> 2) & 3, bx = id >> 4;
  const int m0 = bx * 64;
  const int n0 = by * 64;
  const int k0 = bz * 320;
  float* dst = part + (size_t)bz * ((size_t)B_SZ * H_N);
  __shared__ unsigned short AhL[64 * LDSP], AlL[64 * LDSP];
  __shared__ unsigned short BhL[64 * LDSP];
  const int t = threadIdx.x;
  const int lane = t & 63;
  const int w = t >> 6;
  const int fr = lane & 15;
  const int fq = lane >> 4;
  f32x4 acc[4] = {};
  for (int it = 0; it < 5; ++it) {
    int kb = k0 + it * 64;
#pragma unroll
    for (int j = 0; j < 2; ++j) {
      int c = t + j * 256;
      int row = c >> 3, ko = (c & 7) * 8;
      size_t ga = (size_t)(m0 + row) * KPAD2 + kb + ko;
      size_t gb = (size_t)(n0 + row) * KPAD2 + kb + ko;
      *(short8*)&AhL[row * LDSP + ko] = *(const short8*)&Ah[ga];
      *(short8*)&AlL[row * LDSP + ko] = *(const short8*)&Al[ga];
      *(short8*)&BhL[row * LDSP + ko] = *(const short8*)&Bh[gb];
    }
    __syncthreads();
#pragma unroll
    for (int ks = 0; ks < 2; ++ks) {
      int aoff = (w * 16 + fr) * LDSP + fq * 8 + ks * 32;
      short8 ah = *(const short8*)&AhL[aoff];
      short8 al = *(const short8*)&AlL[aoff];
#pragma unroll
      for (int nt = 0; nt < 4; ++nt) {
        int boff = (nt * 16 + fr) * LDSP + fq * 8 + ks * 32;
        short8 bh = *(const short8*)&BhL[boff];
        acc[nt] = __builtin_amdgcn_mfma_f32_16x16x32_bf16(ah, bh, acc[nt], 0, 0, 0);
        acc[nt] = __builtin_amdgcn_mfma_f32_16x16x32_bf16(al, bh, acc[nt], 0, 0, 0);
      }
    }
    __syncthreads();
  }
  // C layout: col = lane&15, row = (lane>>4)*4 + reg  [m89-verified]
  int mrow = m0 + w * 16 + fq * 4;
#pragma unroll
  for (int nt = 0; nt < 4; ++nt) {
    int ncol = n0 + nt * 16 + fr;
#pragma unroll
    for (int r = 0; r < 4; ++r)
      dst[(size_t)(mrow + r) * H_N + ncol] = acc[nt][r];
  }
}

// ---------------------------------------------------------------------------
// Kernel 3: h1 = relu( relu(sum_z part_z + bb0) @ Wb1^T + bb1 ) via bf16
// MFMA; fused reduce+bias+relu+bf16 in A-staging. BM=64 BN=32, 4 waves.
// ---------------------------------------------------------------------------
#define LDSP2 72
__global__ __launch_bounds__(256) void k_gemm2b(const float* __restrict__ part,
                                                const float* __restrict__ bb0,
                                                const float* __restrict__ Bm,
                                                const float* __restrict__ bias,
                                                float* __restrict__ h1) {
  int flat = blockIdx.x + 32 * blockIdx.y;      // 0..255
  int id = (flat & 7) * 32 + (flat >> 3);       // XCD chunks, x slowest
  const int m0 = (id >> 3) * 64;
  const int n0 = (id & 7) * 32;
  const size_t BH = (size_t)B_SZ * H_N;
  __shared__ unsigned short AtL[64 * LDSP2];
  __shared__ unsigned short BtL[32 * LDSP2];
  const int t = threadIdx.x;
  const int lane = t & 63;
  const int w = t >> 6;
  const int fr = lane & 15;
  const int fq = lane >> 4;
  f32x4 acc[2] = {};
  for (int it = 0; it < 4; ++it) {
    int kb = it * 64;
#pragma unroll
    for (int j = 0; j < 4; ++j) {
      int g = t + j * 256;
      int row = g >> 4, c4 = g & 15;
      size_t base = (size_t)(m0 + row) * H_N + kb + c4 * 4;
      float4 v0 = *(const float4*)&part[base];
      float4 v1 = *(const float4*)&part[base + BH];
      float4 v2 = *(const float4*)&part[base + 2 * BH];
      float4 v3 = *(const float4*)&part[base + 3 * BH];
      float4 bi = *(const float4*)&bb0[kb + c4 * 4];
      ushort4 o;
      o.x = bf16_hi(fmaxf(v0.x + v1.x + v2.x + v3.x + bi.x, 0.f));
      o.y = bf16_hi(fmaxf(v0.y + v1.y + v2.y + v3.y + bi.y, 0.f));
      o.z = bf16_hi(fmaxf(v0.z + v1.z + v2.z + v3.z + bi.z, 0.f));
      o.w = bf16_hi(fmaxf(v0.w + v1.w + v2.w + v3.w + bi.w, 0.f));
      *(ushort4*)&AtL[row * LDSP2 + c4 * 4] = o;
    }
#pragma unroll
    for (int j = 0; j < 2; ++j) {
      int g = t + j * 256;
      int row = g >> 4, c4 = g & 15;
      float4 v = *(const float4*)&Bm[(size_t)(n0 + row) * H_N + kb + c4 * 4];
      ushort4 o;
      o.x = bf16_hi(v.x); o.y = bf16_hi(v.y);
      o.z = bf16_hi(v.z); o.w = bf16_hi(v.w);
      *(ushort4*)&BtL[row * LDSP2 + c4 * 4] = o;
    }
    __syncthreads();
#pragma unroll
    for (int ks = 0; ks < 2; ++ks) {
      short8 a8 = *(const short8*)&AtL[(w * 16 + fr) * LDSP2 + fq * 8 + ks * 32];
#pragma unroll
      for (int nt = 0; nt < 2; ++nt) {
        short8 b8 =
            *(const short8*)&BtL[(nt * 16 + fr) * LDSP2 + fq * 8 + ks * 32];
        acc[nt] = __builtin_amdgcn_mfma_f32_16x16x32_bf16(a8, b8, acc[nt], 0, 0, 0);
      }
    }
    __syncthreads();
  }
  int mrow = m0 + w * 16 + fq * 4;
#pragma unroll
  for (int nt = 0; nt < 2; ++nt) {
    int ncol = n0 + nt * 16 + fr;
    float bs = bias[ncol];
#pragma unroll
    for (int r = 0; r < 4; ++r)
      h1[(size_t)(mrow + r) * H_N + ncol] = fmaxf(acc[nt][r] + bs, 0.f);
  }
}

// ---------------------------------------------------------------------------
// Kernel 4: out[b,:] = h1[b,:] @ Wout^T + bout. One wave per batch row.
// ---------------------------------------------------------------------------
__global__ __launch_bounds__(256) void k_out(const float* __restrict__ h1,
                                             const float* __restrict__ Wout,
                                             const float* __restrict__ bout,
                                             float* __restrict__ out) {
  int w = threadIdx.x >> 6, lane = threadIdx.x & 63;
  int b = blockIdx.x * 4 + w;
  const float* hr = h1 + (size_t)b * H_N;
  float h[4];
#pragma unroll
  for (int j = 0; j < 4; ++j) h[j] = hr[lane + 64 * j];
  float acc[10];
#pragma unroll
  for (int o = 0; o < 10; ++o) {
    float s = 0.f;
#pragma unroll
    for (int j = 0; j < 4; ++j) s += h[j] * Wout[o * H_N + lane + 64 * j];
#pragma unroll
    for (int m = 32; m >= 1; m >>= 1) s += __shfl_xor(s, m);
    acc[o] = s;
  }
  if (lane == 0) {
#pragma unroll
    for (int o = 0; o < 10; ++o) out[(size_t)b * O_N + o] = acc[o] + bout[o];
  }
}

// ---------------------------------------------------------------------------
extern "C" void kernel_launch(void* const* d_in, const int* in_sizes, int n_in,
                              void* d_out, int out_size, void* d_ws,
                              size_t ws_size, hipStream_t stream) {
  (void)in_sizes; (void)n_in; (void)out_size; (void)ws_size;
  const float* x    = (const float*)d_in[0];
  const float* W    = (const float*)d_in[1];
  const float* bvec = (const float*)d_in[2];
  const float* Wb0  = (const float*)d_in[3];
  const float* bb0  = (const float*)d_in[4];
  const float* Wb1  = (const float*)d_in[5];
  const float* bb1  = (const float*)d_in[6];
  const float* Wout = (const float*)d_in[7];
  const float* bout = (const float*)d_in[8];

  float* out   = (float*)d_out;     // B*10
  float* masks = out + B_SZ * O_N;  // B*48

  char* wsb = (char*)d_ws;
  unsigned short* Ch = (unsigned short*)wsb;                // B*KPAD2 us
  unsigned short* Cl = Ch + (size_t)B_SZ * KPAD2;
  unsigned short* Gh = Cl + (size_t)B_SZ * KPAD2;           // H*KPAD2 us
  float* part = (float*)(Gh + (size_t)H_N * KPAD2);         // 4*B*H f32
  float* h1 = part + 4 * (size_t)B_SZ * H_N;                // B*H f32
  // total ~22 MB

  k_ghat<<<dim3(192), 256, 0, stream>>>(W, Wb0, Gh);
  k_seq<<<dim3(512), 256, 0, stream>>>(W, x, bvec, Ch, Cl, masks);
  k_gemm_bf16<<<dim3(32, 4, 4), 256, 0, stream>>>(Ch, Cl, Gh, part);
  k_gemm2b<<<dim3(32, 8), 256, 0, stream>>>(part, bb0, Wb1, bb1, h1);
  k_out<<<dim3(512), 256, 0, stream>>>(h1, Wout, bout, out);
}

// Round 18
// 72.774 us; speedup vs baseline: 4.8804x; 1.0081x over previous
//
#include <hip/hip_runtime.h>

#define B_SZ 2048
#define D_IN 256
#define L_N 48
#define H_N 256
#define O_N 10
#define WROW 303      // D + L - 1
#define LEAF_N 12336  // L*(D+1)
#define KC 2304       // L*L (Gp full layout)
#define KTRI 1176     // 48*49/2 packed lower-tri cols
#define KH2 1224      // KTRI + 48 offs cols
#define KPAD2 1280    // padded K (20 x 64)

using short8 = __attribute__((ext_vector_type(8))) short;
using f32x4  = __attribute__((ext_vector_type(4))) float;

__device__ inline void bf16_split(float v, unsigned short& h, unsigned short& l) {
  unsigned bits = __float_as_uint(v);
  h = (unsigned short)(bits >> 16);
  float hf = __uint_as_float(bits & 0xFFFF0000u);
  float r = v - hf;
  l = (unsigned short)(__float_as_uint(r) >> 16);
}
__device__ inline unsigned short bf16_hi(float v) {
  return (unsigned short)(__float_as_uint(v) >> 16);
}

// ---------------------------------------------------------------------------
// seq body (R12-proven structure; solve made BRANCHLESS so the wave-uniform
// global s_loads hoist/pipeline instead of serializing behind 47 data-
// dependent branches). One wave handles batch row b.
// ---------------------------------------------------------------------------
__device__ __forceinline__ void seq_wave(int b, int lane,
                                         const float* __restrict__ W,
                                         const float* __restrict__ x,
                                         const float* __restrict__ bvec,
                                         unsigned short* __restrict__ Ch,
                                         unsigned short* __restrict__ Cl,
                                         float* __restrict__ mask_out) {
  // in-wave P: lane i = dot(x[b,:], W[i,0:256]); x loads wave-uniform
  float Preg = 0.f;
  if (lane < 48) {
    const float* xr = x + (size_t)b * D_IN;
    const float* wr = W + lane * WROW;
    float a0 = 0.f, a1 = 0.f, a2 = 0.f, a3 = 0.f;
#pragma unroll 4
    for (int d = 0; d < 256; d += 4) {
      a0 = fmaf(xr[d + 0], wr[d + 0], a0);
      a1 = fmaf(xr[d + 1], wr[d + 1], a1);
      a2 = fmaf(xr[d + 2], wr[d + 2], a2);
      a3 = fmaf(xr[d + 3], wr[d + 3], a3);
    }
    Preg = (a0 + a1) + (a2 + a3);
  }

  float whr[47];
#pragma unroll
  for (int k = 0; k < 47; ++k)
    whr[k] = (lane < 48) ? W[lane * WROW + 256 + k] : 0.f;

  float Pb = Preg + ((lane < 48) ? bvec[lane] : 0.f);

  float accA = 0.f, accB = 0.f;
  float offs_lane = 0.f;
  int d_lane = 0;
#pragma unroll
  for (int i = 0; i < 48; ++i) {
    float z = Pb + accA;
    float u = Preg + accB;
    float a_i = fmaxf(z, 0.f);
    bool dpos = z > 0.f;
    float o_i = dpos ? u : 0.f;
    if (lane == i) {
      d_lane = dpos ? 1 : 0;
      offs_lane = a_i - o_i;
    }
    float ab = __shfl(a_i, i);
    float ob = __shfl(o_i, i);
    if (i < 47) {
      accA += whr[i] * ab;
      accB += whr[i] * ob;
    }
  }
  unsigned long long dmask = __ballot(d_lane);

  // BRANCHLESS solve: s[i] = fm_i * (sum_{k<i} wh_i[k] s[k] + (i==lane));
  // wrow via wave-uniform GLOBAL s_loads (SGPR operands, hoistable).
  float s[48];
  s[0] = ((dmask & 1ULL) && lane == 0) ? 1.f : 0.f;
#pragma unroll
  for (int i = 1; i < 48; ++i) {
    const float* wrow = W + i * WROW + 256;
    float t0 = (lane == i) ? 1.f : 0.f;
    float t1 = 0.f, t2 = 0.f, t3 = 0.f;
    int k = 0;
#pragma unroll
    for (; k + 3 < i; k += 4) {
      t0 = fmaf(wrow[k + 0], s[k + 0], t0);
      t1 = fmaf(wrow[k + 1], s[k + 1], t1);
      t2 = fmaf(wrow[k + 2], s[k + 2], t2);
      t3 = fmaf(wrow[k + 3], s[k + 3], t3);
    }
#pragma unroll
    for (; k < i; ++k) t0 = fmaf(wrow[k], s[k], t0);
    float fm = ((dmask >> i) & 1ULL) ? 1.f : 0.f;
    s[i] = fm * ((t0 + t1) + (t2 + t3));
  }

  // packed-tri stores: j = i(i+1)/2 + lane (lane<=i), bf16 hi/lo
  size_t base = (size_t)b * KPAD2;
  if (lane < 48) {
#pragma unroll
    for (int i = 0; i < 48; ++i) {
      if (lane <= i) {
        unsigned short h, l;
        bf16_split(s[i], h, l);
        Ch[base + i * (i + 1) / 2 + lane] = h;
        Cl[base + i * (i + 1) / 2 + lane] = l;
      }
    }
    unsigned short h, l;
    bf16_split(offs_lane, h, l);
    Ch[base + KTRI + lane] = h;
    Cl[base + KTRI + lane] = l;
    mask_out[b * 48 + lane] = d_lane ? 1.f : 0.f;
  }
  for (int e = KH2 + lane; e < KPAD2; e += 64) {
    Ch[base + e] = 0;
    Cl[base + e] = 0;
  }
}

// ---------------------------------------------------------------------------
// D1: blocks [0,768): ghat d-split partials (R7/R8-proven, 3 blocks/CU TLP)
//     Gp[z][h][i*48+k] = sum_{d in chunk z} W[k,d]*Wb0[h,i*257+d]
//     blocks [768,1024): seq batches 0-1023 (4 waves/block).
// ---------------------------------------------------------------------------
__global__ __launch_bounds__(256) void k_front(const float* __restrict__ W,
                                               const float* __restrict__ Wb0,
                                               const float* __restrict__ x,
                                               const float* __restrict__ bvec,
                                               float* __restrict__ Gp,
                                               unsigned short* __restrict__ Ch,
                                               unsigned short* __restrict__ Cl,
                                               float* __restrict__ mask_out) {
  const int bid = blockIdx.x;
  const int t = threadIdx.x;
  if (bid < 768) {
    const int i  = bid % 48;              // layer
    const int rest = bid / 48;            // 0..15
    const int h0 = (rest & 3) * 64;       // h tile
    const int dc = (rest >> 2) * 64;      // d chunk
    __shared__ float At[64][68];          // [d][h]
    __shared__ float Bt[64][68];          // [d][k] (k>=48 zero)
    const int tn = t & 15, tm = t >> 4;
    const int sr = t & 3, sc = t >> 2;    // staging: 4 rows x 64 cols
#pragma unroll
    for (int j = 0; j < 16; ++j) {
      int r = sr + j * 4;
      At[sc][r] = Wb0[(size_t)(h0 + r) * LEAF_N + i * 257 + dc + sc];
      Bt[sc][r] = (r < 48) ? W[r * WROW + dc + sc] : 0.f;
    }
    __syncthreads();
    float acc[4][4] = {};
#pragma unroll 8
    for (int d = 0; d < 64; ++d) {
      float4 av = *(const float4*)&At[d][tm * 4];
      float4 bv = *(const float4*)&Bt[d][tn * 4];
      float aa[4] = {av.x, av.y, av.z, av.w};
      float bb[4] = {bv.x, bv.y, bv.z, bv.w};
#pragma unroll
      for (int ii = 0; ii < 4; ++ii)
#pragma unroll
        for (int jj = 0; jj < 4; ++jj) acc[ii][jj] += aa[ii] * bb[jj];
    }
    if (tn < 12) {
      float* gz = Gp + (size_t)(rest >> 2) * (H_N * KC);
#pragma unroll
      for (int ii = 0; ii < 4; ++ii)
        *(float4*)&gz[(size_t)(h0 + tm * 4 + ii) * KC + i * 48 + tn * 4] =
            make_float4(acc[ii][0], acc[ii][1], acc[ii][2], acc[ii][3]);
    }
  } else {
    const int b = (bid - 768) * 4 + (t >> 6);  // batches 0..1023
    seq_wave(b, t & 63, W, x, bvec, Ch, Cl, mask_out);
  }
}

// ---------------------------------------------------------------------------
// D2: blocks [0,256): gcomb -- sum Gp partials, tri-pack, hi-only bf16 Gh
//     (+offs col + pad).  blocks [256,512): seq batches 1024-2047.
// ---------------------------------------------------------------------------
__global__ __launch_bounds__(256) void k_mid2(const float* __restrict__ Gp,
                                              const float* __restrict__ Wb0,
                                              const float* __restrict__ W,
                                              const float* __restrict__ x,
                                              const float* __restrict__ bvec,
                                              unsigned short* __restrict__ Gh,
                                              unsigned short* __restrict__ Ch,
                                              unsigned short* __restrict__ Cl,
                                              float* __restrict__ mask_out) {
  const int bid = blockIdx.x;
  const int t = threadIdx.x;
  if (bid < 256) {
    const int h = bid;
    for (int j = t; j < KTRI; j += 256) {
      // j -> (i,k), k<=i
      int i = (int)((sqrtf((float)(8 * j + 1)) - 1.f) * 0.5f);
      while ((i + 1) * (i + 2) / 2 <= j) ++i;
      while (i * (i + 1) / 2 > j) --i;
      int k = j - i * (i + 1) / 2;
      size_t g = (size_t)h * KC + i * 48 + k;
      float v = Gp[g] + Gp[(size_t)H_N * KC + g] +
                Gp[2 * (size_t)H_N * KC + g] + Gp[3 * (size_t)H_N * KC + g];
      Gh[(size_t)h * KPAD2 + j] = bf16_hi(v);
    }
    if (t < 48) {  // offs col
      Gh[(size_t)h * KPAD2 + KTRI + t] =
          bf16_hi(Wb0[(size_t)h * LEAF_N + t * 257 + 256]);
    }
    for (int e = KH2 + t; e < KPAD2; e += 256) Gh[(size_t)h * KPAD2 + e] = 0;
    return;
  }
  const int b = 1024 + (bid - 256) * 4 + (t >> 6);  // batches 1024..2047
  seq_wave(b, t & 63, W, x, bvec, Ch, Cl, mask_out);
}

// ---------------------------------------------------------------------------
// Kernel 2: big GEMM, 2-term bf16 MFMA: acc = Ah*Bh + Al*Bh.
// 4 waves, LDS-staged, LDSP=88. K=1280 split 4x320. XCD-chunk-swizzled.
// ---------------------------------------------------------------------------
#define LDSP 88
__global__ __launch_bounds__(256) void k_gemm_bf16(
    const unsigned short* __restrict__ Ah, const unsigned short* __restrict__ Al,
    const unsigned short* __restrict__ Bh,
    float* __restrict__ part) {
  int flat = blockIdx.x + 32 * blockIdx.y + 128 * blockIdx.z;  // 0..511
  int id = (flat & 7) * 64 + (flat >> 3);                      // XCD chunks
  const int bz = id & 3, by = (id >> 2) & 3, bx = id >> 4;
  const int m0 = bx * 64;
  const int n0 = by * 64;
  const int k0 = bz * 320;
  float* dst = part + (size_t)bz * ((size_t)B_SZ * H_N);
  __shared__ unsigned short AhL[64 * LDSP], AlL[64 * LDSP];
  __shared__ unsigned short BhL[64 * LDSP];
  const int t = threadIdx.x;
  const int lane = t & 63;
  const int w = t >> 6;
  const int fr = lane & 15;
  const int fq = lane >> 4;
  f32x4 acc[4] = {};
  for (int it = 0; it < 5; ++it) {
    int kb = k0 + it * 64;
#pragma unroll
    for (int j = 0; j < 2; ++j) {
      int c = t + j * 256;
      int row = c >> 3, ko = (c & 7) * 8;
      size_t ga = (size_t)(m0 + row) * KPAD2 + kb + ko;
      size_t gb = (size_t)(n0 + row) * KPAD2 + kb + ko;
      *(short8*)&AhL[row * LDSP + ko] = *(const short8*)&Ah[ga];
      *(short8*)&AlL[row * LDSP + ko] = *(const short8*)&Al[ga];
      *(short8*)&BhL[row * LDSP + ko] = *(const short8*)&Bh[gb];
    }
    __syncthreads();
#pragma unroll
    for (int ks = 0; ks < 2; ++ks) {
      int aoff = (w * 16 + fr) * LDSP + fq * 8 + ks * 32;
      short8 ah = *(const short8*)&AhL[aoff];
      short8 al = *(const short8*)&AlL[aoff];
#pragma unroll
      for (int nt = 0; nt < 4; ++nt) {
        int boff = (nt * 16 + fr) * LDSP + fq * 8 + ks * 32;
        short8 bh = *(const short8*)&BhL[boff];
        acc[nt] = __builtin_amdgcn_mfma_f32_16x16x32_bf16(ah, bh, acc[nt], 0, 0, 0);
        acc[nt] = __builtin_amdgcn_mfma_f32_16x16x32_bf16(al, bh, acc[nt], 0, 0, 0);
      }
    }
    __syncthreads();
  }
  // C layout: col = lane&15, row = (lane>>4)*4 + reg  [m89-verified]
  int mrow = m0 + w * 16 + fq * 4;
#pragma unroll
  for (int nt = 0; nt < 4; ++nt) {
    int ncol = n0 + nt * 16 + fr;
#pragma unroll
    for (int r = 0; r < 4; ++r)
      dst[(size_t)(mrow + r) * H_N + ncol] = acc[nt][r];
  }
}

// ---------------------------------------------------------------------------
// Kernel 3: h1 = relu( relu(sum_z part_z + bb0) @ Wb1^T + bb1 ) via bf16
// MFMA; fused reduce+bias+relu+bf16 in A-staging. BM=64 BN=32, 4 waves.
// ---------------------------------------------------------------------------
#define LDSP2 72
__global__ __launch_bounds__(256) void k_gemm2b(const float* __restrict__ part,
                                                const float* __restrict__ bb0,
                                                const float* __restrict__ Bm,
                                                const float* __restrict__ bias,
                                                float* __restrict__ h1) {
  int flat = blockIdx.x + 32 * blockIdx.y;      // 0..255
  int id = (flat & 7) * 32 + (flat >> 3);       // XCD chunks, x slowest
  const int m0 = (id >> 3) * 64;
  const int n0 = (id & 7) * 32;
  const size_t BH = (size_t)B_SZ * H_N;
  __shared__ unsigned short AtL[64 * LDSP2];
  __shared__ unsigned short BtL[32 * LDSP2];
  const int t = threadIdx.x;
  const int lane = t & 63;
  const int w = t >> 6;
  const int fr = lane & 15;
  const int fq = lane >> 4;
  f32x4 acc[2] = {};
  for (int it = 0; it < 4; ++it) {
    int kb = it * 64;
#pragma unroll
    for (int j = 0; j < 4; ++j) {
      int g = t + j * 256;
      int row = g >> 4, c4 = g & 15;
      size_t base = (size_t)(m0 + row) * H_N + kb + c4 * 4;
      float4 v0 = *(const float4*)&part[base];
      float4 v1 = *(const float4*)&part[base + BH];
      float4 v2 = *(const float4*)&part[base + 2 * BH];
      float4 v3 = *(const float4*)&part[base + 3 * BH];
      float4 bi = *(const float4*)&bb0[kb + c4 * 4];
      ushort4 o;
      o.x = bf16_hi(fmaxf(v0.x + v1.x + v2.x + v3.x + bi.x, 0.f));
      o.y = bf16_hi(fmaxf(v0.y + v1.y + v2.y + v3.y + bi.y, 0.f));
      o.z = bf16_hi(fmaxf(v0.z + v1.z + v2.z + v3.z + bi.z, 0.f));
      o.w = bf16_hi(fmaxf(v0.w + v1.w + v2.w + v3.w + bi.w, 0.f));
      *(ushort4*)&AtL[row * LDSP2 + c4 * 4] = o;
    }
#pragma unroll
    for (int j = 0; j < 2; ++j) {
      int g = t + j * 256;
      int row = g >> 4, c4 = g & 15;
      float4 v = *(const float4*)&Bm[(size_t)(n0 + row) * H_N + kb + c4 * 4];
      ushort4 o;
      o.x = bf16_hi(v.x); o.y = bf16_hi(v.y);
      o.z = bf16_hi(v.z); o.w = bf16_hi(v.w);
      *(ushort4*)&BtL[row * LDSP2 + c4 * 4] = o;
    }
    __syncthreads();
#pragma unroll
    for (int ks = 0; ks < 2; ++ks) {
      short8 a8 = *(const short8*)&AtL[(w * 16 + fr) * LDSP2 + fq * 8 + ks * 32];
#pragma unroll
      for (int nt = 0; nt < 2; ++nt) {
        short8 b8 =
            *(const short8*)&BtL[(nt * 16 + fr) * LDSP2 + fq * 8 + ks * 32];
        acc[nt] = __builtin_amdgcn_mfma_f32_16x16x32_bf16(a8, b8, acc[nt], 0, 0, 0);
      }
    }
    __syncthreads();
  }
  int mrow = m0 + w * 16 + fq * 4;
#pragma unroll
  for (int nt = 0; nt < 2; ++nt) {
    int ncol = n0 + nt * 16 + fr;
    float bs = bias[ncol];
#pragma unroll
    for (int r = 0; r < 4; ++r)
      h1[(size_t)(mrow + r) * H_N + ncol] = fmaxf(acc[nt][r] + bs, 0.f);
  }
}

// ---------------------------------------------------------------------------
// Kernel 4: out[b,:] = h1[b,:] @ Wout^T + bout. One wave per batch row.
// ---------------------------------------------------------------------------
__global__ __launch_bounds__(256) void k_out(const float* __restrict__ h1,
                                             const float* __restrict__ Wout,
                                             const float* __restrict__ bout,
                                             float* __restrict__ out) {
  int w = threadIdx.x >> 6, lane = threadIdx.x & 63;
  int b = blockIdx.x * 4 + w;
  const float* hr = h1 + (size_t)b * H_N;
  float h[4];
#pragma unroll
  for (int j = 0; j < 4; ++j) h[j] = hr[lane + 64 * j];
  float acc[10];
#pragma unroll
  for (int o = 0; o < 10; ++o) {
    float s = 0.f;
#pragma unroll
    for (int j = 0; j < 4; ++j) s += h[j] * Wout[o * H_N + lane + 64 * j];
#pragma unroll
    for (int m = 32; m >= 1; m >>= 1) s += __shfl_xor(s, m);
    acc[o] = s;
  }
  if (lane == 0) {
#pragma unroll
    for (int o = 0; o < 10; ++o) out[(size_t)b * O_N + o] = acc[o] + bout[o];
  }
}

// ---------------------------------------------------------------------------
extern "C" void kernel_launch(void* const* d_in, const int* in_sizes, int n_in,
                              void* d_out, int out_size, void* d_ws,
                              size_t ws_size, hipStream_t stream) {
  (void)in_sizes; (void)n_in; (void)out_size; (void)ws_size;
  const float* x    = (const float*)d_in[0];
  const float* W    = (const float*)d_in[1];
  const float* bvec = (const float*)d_in[2];
  const float* Wb0  = (const float*)d_in[3];
  const float* bb0  = (const float*)d_in[4];
  const float* Wb1  = (const float*)d_in[5];
  const float* bb1  = (const float*)d_in[6];
  const float* Wout = (const float*)d_in[7];
  const float* bout = (const float*)d_in[8];

  float* out   = (float*)d_out;     // B*10
  float* masks = out + B_SZ * O_N;  // B*48

  char* wsb = (char*)d_ws;
  unsigned short* Ch = (unsigned short*)wsb;                // B*KPAD2 us
  unsigned short* Cl = Ch + (size_t)B_SZ * KPAD2;
  unsigned short* Gh = Cl + (size_t)B_SZ * KPAD2;           // H*KPAD2 us
  float* part = (float*)(Gh + (size_t)H_N * KPAD2);         // 4*B*H f32
  float* h1 = part + 4 * (size_t)B_SZ * H_N;                // B*H f32
  float* Gp = h1 + (size_t)B_SZ * H_N;                      // 4*H*KC f32
  // total ~31 MB

  k_front<<<dim3(1024), 256, 0, stream>>>(W, Wb0, x, bvec, Gp, Ch, Cl, masks);
  k_mid2<<<dim3(512), 256, 0, stream>>>(Gp, Wb0, W, x, bvec, Gh, Ch, Cl,
                                        masks);
  k_gemm_bf16<<<dim3(32, 4, 4), 256, 0, stream>>>(Ch, Cl, Gh, part);
  k_gemm2b<<<dim3(32, 8), 256, 0, stream>>>(part, bb0, Wb1, bb1, h1);
  k_out<<<dim3(512), 256, 0, stream>>>(h1, Wout, bout, out);
}

// Round 19
// 60.252 us; speedup vs baseline: 5.8947x; 1.2078x over previous
//
#include <hip/hip_runtime.h>

#define B_SZ 2048
#define D_IN 256
#define L_N 48
#define H_N 256
#define O_N 10
#define WROW 303      // D + L - 1
#define LEAF_N 12336  // L*(D+1)
#define KTRI 1176     // 48*49/2 packed lower-tri cols
#define KH2 1224      // KTRI + 48 offs cols
#define KPAD2 1280    // padded K (20 x 64)

using short8 = __attribute__((ext_vector_type(8))) short;
using f32x4  = __attribute__((ext_vector_type(4))) float;

__device__ inline void bf16_split(float v, unsigned short& h, unsigned short& l) {
  unsigned bits = __float_as_uint(v);
  h = (unsigned short)(bits >> 16);
  float hf = __uint_as_float(bits & 0xFFFF0000u);
  float r = v - hf;
  l = (unsigned short)(__float_as_uint(r) >> 16);
}
__device__ inline unsigned short bf16_hi(float v) {
  return (unsigned short)(__float_as_uint(v) >> 16);
}

// ---------------------------------------------------------------------------
// seq body: R12-proven EXACT form (in-wave P with global W reads; branchy
// solve with wave-uniform GLOBAL s_loads -> SGPR operands, no VGPR spill).
// ---------------------------------------------------------------------------
__device__ __forceinline__ void seq_wave(int b, int lane,
                                         const float* __restrict__ W,
                                         const float* __restrict__ x,
                                         const float* __restrict__ bvec,
                                         unsigned short* __restrict__ Ch,
                                         unsigned short* __restrict__ Cl,
                                         float* __restrict__ mask_out) {
  float Preg = 0.f;
  if (lane < 48) {
    const float* xr = x + (size_t)b * D_IN;
    const float* wr = W + lane * WROW;
    float a0 = 0.f, a1 = 0.f, a2 = 0.f, a3 = 0.f;
#pragma unroll 4
    for (int d = 0; d < 256; d += 4) {
      a0 = fmaf(xr[d + 0], wr[d + 0], a0);
      a1 = fmaf(xr[d + 1], wr[d + 1], a1);
      a2 = fmaf(xr[d + 2], wr[d + 2], a2);
      a3 = fmaf(xr[d + 3], wr[d + 3], a3);
    }
    Preg = (a0 + a1) + (a2 + a3);
  }

  float whr[47];
#pragma unroll
  for (int k = 0; k < 47; ++k)
    whr[k] = (lane < 48) ? W[lane * WROW + 256 + k] : 0.f;

  float Pb = Preg + ((lane < 48) ? bvec[lane] : 0.f);

  float accA = 0.f, accB = 0.f;
  float offs_lane = 0.f;
  int d_lane = 0;
#pragma unroll
  for (int i = 0; i < 48; ++i) {
    float z = Pb + accA;
    float u = Preg + accB;
    float a_i = fmaxf(z, 0.f);
    bool dpos = z > 0.f;
    float o_i = dpos ? u : 0.f;
    if (lane == i) {
      d_lane = dpos ? 1 : 0;
      offs_lane = a_i - o_i;
    }
    float ab = __shfl(a_i, i);
    float ob = __shfl(o_i, i);
    if (i < 47) {
      accA += whr[i] * ab;
      accB += whr[i] * ob;
    }
  }
  unsigned long long dmask = __ballot(d_lane);

  float s[48];
  s[0] = ((dmask & 1ULL) && lane == 0) ? 1.f : 0.f;
#pragma unroll
  for (int i = 1; i < 48; ++i) {
    if ((dmask >> i) & 1ULL) {
      const float* wrow = W + i * WROW + 256;
      float t0 = (lane == i) ? 1.f : 0.f;
      float t1 = 0.f, t2 = 0.f, t3 = 0.f;
      int k = 0;
#pragma unroll
      for (; k + 3 < i; k += 4) {
        t0 += wrow[k + 0] * s[k + 0];
        t1 += wrow[k + 1] * s[k + 1];
        t2 += wrow[k + 2] * s[k + 2];
        t3 += wrow[k + 3] * s[k + 3];
      }
#pragma unroll
      for (; k < i; ++k) t0 += wrow[k] * s[k];
      s[i] = (t0 + t1) + (t2 + t3);
    } else {
      s[i] = 0.f;
    }
  }

  size_t base = (size_t)b * KPAD2;
  if (lane < 48) {
#pragma unroll
    for (int i = 0; i < 48; ++i) {
      if (lane <= i) {
        unsigned short h, l;
        bf16_split(s[i], h, l);
        Ch[base + i * (i + 1) / 2 + lane] = h;
        Cl[base + i * (i + 1) / 2 + lane] = l;
      }
    }
    unsigned short h, l;
    bf16_split(offs_lane, h, l);
    Ch[base + KTRI + lane] = h;
    Cl[base + KTRI + lane] = l;
    mask_out[b * 48 + lane] = d_lane ? 1.f : 0.f;
  }
  for (int e = KH2 + lane; e < KPAD2; e += 64) {
    Ch[base + e] = 0;
    Cl[base + e] = 0;
  }
}

// ---------------------------------------------------------------------------
// Kernel 1 (merged, 704 blocks x 256 thr):
// blocks [0,192): ghat via MFMA -- per (i, 64-h tile): C[h][k<=i] =
//   sum_d Wb0[h,i*257+d]*W[k,d], K=256 in 4 rounds; fp32->bf16 hi/lo
//   INLINE in staging (each element read once); 2-term MFMA (Ah*Bh+Al*Bh);
//   n-tile tri-skip. Same verified fragment addressing as k_gemm2b.
// blocks [192,704): seq, 4 waves, one batch row each (R12-proven).
// ---------------------------------------------------------------------------
#define GLP 72  // ghat LDS row stride (ushorts); 144B, 16B-aligned
__global__ __launch_bounds__(256) void k1(const float* __restrict__ W,
                                          const float* __restrict__ Wb0,
                                          const float* __restrict__ x,
                                          const float* __restrict__ bvec,
                                          unsigned short* __restrict__ Gh,
                                          unsigned short* __restrict__ Ch,
                                          unsigned short* __restrict__ Cl,
                                          float* __restrict__ mask_out) {
  const int bid = blockIdx.x;
  const int t = threadIdx.x;
  if (bid < 192) {
    __shared__ unsigned short AhL[64 * GLP], AlL[64 * GLP], BhL[48 * GLP];
    const int i  = bid % 48;
    const int h0 = (bid / 48) * 64;
    const int w = t >> 6;
    const int lane = t & 63;
    const int fr = lane & 15;
    const int fq = lane >> 4;
    const int arow = t >> 4;        // A staging: 16 rows/pass
    const int ac0 = (t & 15) * 4;   // 4 consecutive cols
    f32x4 acc[3] = {};
    for (int it = 0; it < 4; ++it) {
      const int dc = it * 64;
      __syncthreads();
      // A: 64 rows x 64 cols fp32 -> split hi/lo (dword loads: i*257 odd)
#pragma unroll
      for (int p = 0; p < 4; ++p) {
        int r = arow + p * 16;
        const float* src = Wb0 + (size_t)(h0 + r) * LEAF_N + i * 257 + dc + ac0;
        float v0 = src[0], v1 = src[1], v2 = src[2], v3 = src[3];
        ushort4 hh, ll;
        bf16_split(v0, hh.x, ll.x);
        bf16_split(v1, hh.y, ll.y);
        bf16_split(v2, hh.z, ll.z);
        bf16_split(v3, hh.w, ll.w);
        *(ushort4*)&AhL[r * GLP + ac0] = hh;
        *(ushort4*)&AlL[r * GLP + ac0] = ll;
      }
      // B: W[k, dc+c] bf16-hi, k<48
      for (int e = t; e < 48 * 64; e += 256) {
        int r = e >> 6, c = e & 63;
        BhL[r * GLP + c] = bf16_hi(W[r * WROW + dc + c]);
      }
      __syncthreads();
#pragma unroll
      for (int ks = 0; ks < 2; ++ks) {
        int aoff = (w * 16 + fr) * GLP + fq * 8 + ks * 32;
        short8 ah = *(const short8*)&AhL[aoff];
        short8 al = *(const short8*)&AlL[aoff];
#pragma unroll
        for (int nt = 0; nt < 3; ++nt) {
          if (nt * 16 <= i) {  // tri-skip (i uniform -> uniform branch)
            short8 bh = *(const short8*)&BhL[(nt * 16 + fr) * GLP + fq * 8 + ks * 32];
            acc[nt] = __builtin_amdgcn_mfma_f32_16x16x32_bf16(ah, bh, acc[nt], 0, 0, 0);
            acc[nt] = __builtin_amdgcn_mfma_f32_16x16x32_bf16(al, bh, acc[nt], 0, 0, 0);
          }
        }
      }
    }
    // epilogue: C row = w*16 + fq*4 + r (h index), col = nt*16 + fr (k)
    const int tb = i * (i + 1) / 2;
#pragma unroll
    for (int nt = 0; nt < 3; ++nt) {
      int k = nt * 16 + fr;
      if (k <= i) {
#pragma unroll
        for (int r = 0; r < 4; ++r) {
          int m = w * 16 + fq * 4 + r;
          Gh[(size_t)(h0 + m) * KPAD2 + tb + k] = bf16_hi(acc[nt][r]);
        }
      }
    }
    if (t < 64)  // offs column for this i
      Gh[(size_t)(h0 + t) * KPAD2 + KTRI + i] =
          bf16_hi(Wb0[(size_t)(h0 + t) * LEAF_N + i * 257 + 256]);
    if (i == 0) {  // pad [KH2, KPAD2)
      for (int e = t; e < 64 * (KPAD2 - KH2); e += 256) {
        int r = e / (KPAD2 - KH2), c = e - r * (KPAD2 - KH2);
        Gh[(size_t)(h0 + r) * KPAD2 + KH2 + c] = 0;
      }
    }
    return;
  }
  const int b = (bid - 192) * 4 + (t >> 6);  // batches 0..2047
  seq_wave(b, t & 63, W, x, bvec, Ch, Cl, mask_out);
}

// ---------------------------------------------------------------------------
// Kernel 2: big GEMM, 2-term bf16 MFMA: acc = Ah*Bh + Al*Bh.
// 4 waves, LDS-staged, LDSP=88. K=1280 split 4x320. XCD-chunk-swizzled.
// ---------------------------------------------------------------------------
#define LDSP 88
__global__ __launch_bounds__(256) void k_gemm_bf16(
    const unsigned short* __restrict__ Ah, const unsigned short* __restrict__ Al,
    const unsigned short* __restrict__ Bh,
    float* __restrict__ part) {
  int flat = blockIdx.x + 32 * blockIdx.y + 128 * blockIdx.z;  // 0..511
  int id = (flat & 7) * 64 + (flat >> 3);                      // XCD chunks
  const int bz = id & 3, by = (id >> 2) & 3, bx = id >> 4;
  const int m0 = bx * 64;
  const int n0 = by * 64;
  const int k0 = bz * 320;
  float* dst = part + (size_t)bz * ((size_t)B_SZ * H_N);
  __shared__ unsigned short AhL[64 * LDSP], AlL[64 * LDSP];
  __shared__ unsigned short BhL[64 * LDSP];
  const int t = threadIdx.x;
  const int lane = t & 63;
  const int w = t >> 6;
  const int fr = lane & 15;
  const int fq = lane >> 4;
  f32x4 acc[4] = {};
  for (int it = 0; it < 5; ++it) {
    int kb = k0 + it * 64;
#pragma unroll
    for (int j = 0; j < 2; ++j) {
      int c = t + j * 256;
      int row = c >> 3, ko = (c & 7) * 8;
      size_t ga = (size_t)(m0 + row) * KPAD2 + kb + ko;
      size_t gb = (size_t)(n0 + row) * KPAD2 + kb + ko;
      *(short8*)&AhL[row * LDSP + ko] = *(const short8*)&Ah[ga];
      *(short8*)&AlL[row * LDSP + ko] = *(const short8*)&Al[ga];
      *(short8*)&BhL[row * LDSP + ko] = *(const short8*)&Bh[gb];
    }
    __syncthreads();
#pragma unroll
    for (int ks = 0; ks < 2; ++ks) {
      int aoff = (w * 16 + fr) * LDSP + fq * 8 + ks * 32;
      short8 ah = *(const short8*)&AhL[aoff];
      short8 al = *(const short8*)&AlL[aoff];
#pragma unroll
      for (int nt = 0; nt < 4; ++nt) {
        int boff = (nt * 16 + fr) * LDSP + fq * 8 + ks * 32;
        short8 bh = *(const short8*)&BhL[boff];
        acc[nt] = __builtin_amdgcn_mfma_f32_16x16x32_bf16(ah, bh, acc[nt], 0, 0, 0);
        acc[nt] = __builtin_amdgcn_mfma_f32_16x16x32_bf16(al, bh, acc[nt], 0, 0, 0);
      }
    }
    __syncthreads();
  }
  // C layout: col = lane&15, row = (lane>>4)*4 + reg  [m89-verified]
  int mrow = m0 + w * 16 + fq * 4;
#pragma unroll
  for (int nt = 0; nt < 4; ++nt) {
    int ncol = n0 + nt * 16 + fr;
#pragma unroll
    for (int r = 0; r < 4; ++r)
      dst[(size_t)(mrow + r) * H_N + ncol] = acc[nt][r];
  }
}

// ---------------------------------------------------------------------------
// Kernel 3: h1 = relu( relu(sum_z part_z + bb0) @ Wb1^T + bb1 ) via bf16
// MFMA; fused reduce+bias+relu+bf16 in A-staging. BM=64 BN=32, 4 waves.
// ---------------------------------------------------------------------------
#define LDSP2 72
__global__ __launch_bounds__(256) void k_gemm2b(const float* __restrict__ part,
                                                const float* __restrict__ bb0,
                                                const float* __restrict__ Bm,
                                                const float* __restrict__ bias,
                                                float* __restrict__ h1) {
  int flat = blockIdx.x + 32 * blockIdx.y;      // 0..255
  int id = (flat & 7) * 32 + (flat >> 3);       // XCD chunks, x slowest
  const int m0 = (id >> 3) * 64;
  const int n0 = (id & 7) * 32;
  const size_t BH = (size_t)B_SZ * H_N;
  __shared__ unsigned short AtL[64 * LDSP2];
  __shared__ unsigned short BtL[32 * LDSP2];
  const int t = threadIdx.x;
  const int lane = t & 63;
  const int w = t >> 6;
  const int fr = lane & 15;
  const int fq = lane >> 4;
  f32x4 acc[2] = {};
  for (int it = 0; it < 4; ++it) {
    int kb = it * 64;
#pragma unroll
    for (int j = 0; j < 4; ++j) {
      int g = t + j * 256;
      int row = g >> 4, c4 = g & 15;
      size_t base = (size_t)(m0 + row) * H_N + kb + c4 * 4;
      float4 v0 = *(const float4*)&part[base];
      float4 v1 = *(const float4*)&part[base + BH];
      float4 v2 = *(const float4*)&part[base + 2 * BH];
      float4 v3 = *(const float4*)&part[base + 3 * BH];
      float4 bi = *(const float4*)&bb0[kb + c4 * 4];
      ushort4 o;
      o.x = bf16_hi(fmaxf(v0.x + v1.x + v2.x + v3.x + bi.x, 0.f));
      o.y = bf16_hi(fmaxf(v0.y + v1.y + v2.y + v3.y + bi.y, 0.f));
      o.z = bf16_hi(fmaxf(v0.z + v1.z + v2.z + v3.z + bi.z, 0.f));
      o.w = bf16_hi(fmaxf(v0.w + v1.w + v2.w + v3.w + bi.w, 0.f));
      *(ushort4*)&AtL[row * LDSP2 + c4 * 4] = o;
    }
#pragma unroll
    for (int j = 0; j < 2; ++j) {
      int g = t + j * 256;
      int row = g >> 4, c4 = g & 15;
      float4 v = *(const float4*)&Bm[(size_t)(n0 + row) * H_N + kb + c4 * 4];
      ushort4 o;
      o.x = bf16_hi(v.x); o.y = bf16_hi(v.y);
      o.z = bf16_hi(v.z); o.w = bf16_hi(v.w);
      *(ushort4*)&BtL[row * LDSP2 + c4 * 4] = o;
    }
    __syncthreads();
#pragma unroll
    for (int ks = 0; ks < 2; ++ks) {
      short8 a8 = *(const short8*)&AtL[(w * 16 + fr) * LDSP2 + fq * 8 + ks * 32];
#pragma unroll
      for (int nt = 0; nt < 2; ++nt) {
        short8 b8 =
            *(const short8*)&BtL[(nt * 16 + fr) * LDSP2 + fq * 8 + ks * 32];
        acc[nt] = __builtin_amdgcn_mfma_f32_16x16x32_bf16(a8, b8, acc[nt], 0, 0, 0);
      }
    }
    __syncthreads();
  }
  int mrow = m0 + w * 16 + fq * 4;
#pragma unroll
  for (int nt = 0; nt < 2; ++nt) {
    int ncol = n0 + nt * 16 + fr;
    float bs = bias[ncol];
#pragma unroll
    for (int r = 0; r < 4; ++r)
      h1[(size_t)(mrow + r) * H_N + ncol] = fmaxf(acc[nt][r] + bs, 0.f);
  }
}

// ---------------------------------------------------------------------------
// Kernel 4: out[b,:] = h1[b,:] @ Wout^T + bout. One wave per batch row.
// ---------------------------------------------------------------------------
__global__ __launch_bounds__(256) void k_out(const float* __restrict__ h1,
                                             const float* __restrict__ Wout,
                                             const float* __restrict__ bout,
                                             float* __restrict__ out) {
  int w = threadIdx.x >> 6, lane = threadIdx.x & 63;
  int b = blockIdx.x * 4 + w;
  const float* hr = h1 + (size_t)b * H_N;
  float h[4];
#pragma unroll
  for (int j = 0; j < 4; ++j) h[j] = hr[lane + 64 * j];
  float acc[10];
#pragma unroll
  for (int o = 0; o < 10; ++o) {
    float s = 0.f;
#pragma unroll
    for (int j = 0; j < 4; ++j) s += h[j] * Wout[o * H_N + lane + 64 * j];
#pragma unroll
    for (int m = 32; m >= 1; m >>= 1) s += __shfl_xor(s, m);
    acc[o] = s;
  }
  if (lane == 0) {
#pragma unroll
    for (int o = 0; o < 10; ++o) out[(size_t)b * O_N + o] = acc[o] + bout[o];
  }
}

// ---------------------------------------------------------------------------
extern "C" void kernel_launch(void* const* d_in, const int* in_sizes, int n_in,
                              void* d_out, int out_size, void* d_ws,
                              size_t ws_size, hipStream_t stream) {
  (void)in_sizes; (void)n_in; (void)out_size; (void)ws_size;
  const float* x    = (const float*)d_in[0];
  const float* W    = (const float*)d_in[1];
  const float* bvec = (const float*)d_in[2];
  const float* Wb0  = (const float*)d_in[3];
  const float* bb0  = (const float*)d_in[4];
  const float* Wb1  = (const float*)d_in[5];
  const float* bb1  = (const float*)d_in[6];
  const float* Wout = (const float*)d_in[7];
  const float* bout = (const float*)d_in[8];

  float* out   = (float*)d_out;     // B*10
  float* masks = out + B_SZ * O_N;  // B*48

  char* wsb = (char*)d_ws;
  unsigned short* Ch = (unsigned short*)wsb;                // B*KPAD2 us
  unsigned short* Cl = Ch + (size_t)B_SZ * KPAD2;
  unsigned short* Gh = Cl + (size_t)B_SZ * KPAD2;           // H*KPAD2 us
  float* part = (float*)(Gh + (size_t)H_N * KPAD2);         // 4*B*H f32
  float* h1 = part + 4 * (size_t)B_SZ * H_N;                // B*H f32
  // total ~22 MB

  k1<<<dim3(704), 256, 0, stream>>>(W, Wb0, x, bvec, Gh, Ch, Cl, masks);
  k_gemm_bf16<<<dim3(32, 4, 4), 256, 0, stream>>>(Ch, Cl, Gh, part);
  k_gemm2b<<<dim3(32, 8), 256, 0, stream>>>(part, bb0, Wb1, bb1, h1);
  k_out<<<dim3(512), 256, 0, stream>>>(h1, Wout, bout, out);
}